// Round 18
// baseline (5237.849 us; speedup 1.0000x reference)
//
#include <hip/hip_runtime.h>
#include <stdint.h>

#pragma clang fp contract(off)

#define T_STEPS 784
#define NH 64
#define NOUT 10

typedef __attribute__((ext_vector_type(2))) float f32x2;
typedef __attribute__((ext_vector_type(4))) float f32x4;

// v_pk_fma_f32: per-half independent IEEE-rn f32 fma (verified bit-exact r8/r9/r12/r16).
#define PK_LO(acc, s, wp) \
    asm("v_pk_fma_f32 %0, %1, %2, %0 op_sel:[0,0,0] op_sel_hi:[1,0,1]" \
        : "+v"(acc) : "v"(s), "v"(wp))
#define PK_HI(acc, s, wp) \
    asm("v_pk_fma_f32 %0, %1, %2, %0 op_sel:[0,1,0] op_sel_hi:[1,1,1]" \
        : "+v"(acc) : "v"(s), "v"(wp))

// th = (th + mem*co) - ((th-0.5)*0.02), each op rounded, old mem  (r3-verified)
#define THUP(tt, mm) { const float p_ = (mm) * co; const float q_ = (tt) + p_; \
    const float r_ = (tt) - 0.5f; const float rs_ = r_ * 0.02f; (tt) = q_ - rs_; }
// mem = (spike ? 0 : mem*0.5) + h   (r3-verified)
#define MEMUP(mm, ss, hh) { const float md_ = (mm) * 0.5f; \
    const float keep_ = (ss) ? 0.0f : md_; (mm) = keep_ + (hh); }

// EIGHT batch rows per wave (4 pk-pairs AB/CD/EF/GH); lane = neuron j.
// Rationale (r17 post-mortem): the dot is a numerics-locked sequential fma
// chain per row; ILP must come from independent rows. 4 chains/layer makes the
// dot issue-bound (1024 cyc issue vs 256 cyc chain latency) even at 1
// wave/SIMD, where the unified register budget is 512 (no AGPR-copy pressure,
// no spill). LDS spike broadcast via uniform-address b128, shufflevector
// names lo/hi pairs directly (r12/r16-verified codegen).

__global__ __attribute__((amdgpu_flat_work_group_size(64, 64)))
__attribute__((amdgpu_waves_per_eu(1)))
void tesnn_main_kernel(
    const float* __restrict__ input,
    const float* __restrict__ W1, const float* __restrict__ b1,
    const float* __restrict__ W2, const float* __restrict__ b2,
    const float* __restrict__ W3, const float* __restrict__ b3,
    const float* __restrict__ Wo, const float* __restrict__ bo,
    const float* __restrict__ ce,
    float* __restrict__ out, int N)
{
    __shared__ alignas(16) f32x2 sAB[NH];   // spikes {A,B}, reused L1->L2->L3
    __shared__ alignas(16) f32x2 sCD[NH];
    __shared__ alignas(16) f32x2 sEF[NH];
    __shared__ alignas(16) f32x2 sGH[NH];

    const int lane = threadIdx.x;
    const int n0 = blockIdx.x * 8;
    if (n0 >= N) return;
#define CLAMPN(i) ((n0 + (i) < N) ? n0 + (i) : N - 1)
    const int nA = CLAMPN(0), nB = CLAMPN(1), nC = CLAMPN(2), nD = CLAMPN(3);
    const int nE = CLAMPN(4), nF = CLAMPN(5), nG = CLAMPN(6), nH = CLAMPN(7);

    // ---- per-lane weights (lane = neuron j) ----
    const float w1 = W1[lane];
    const float bb1 = b1[lane];
    const float bb2 = b2[lane];
    const float bb3 = b3[lane];

    f32x2 wp2[32], wp3[32];     // pairs {w[2g], w[2g+1]} of row j
#pragma unroll
    for (int i = 0; i < 32; ++i) {
        wp2[i] = *reinterpret_cast<const f32x2*>(&W2[(size_t)lane * NH + 2 * i]);
        wp3[i] = *reinterpret_cast<const f32x2*>(&W3[(size_t)lane * NH + 2 * i]);
    }

    // ---- state: X-macro over 8 row suffixes ----
#define ROWS(M) M(A) M(B) M(C) M(D) M(E) M(F) M(G) M(H)
#define DECL_STATE(R) \
    float m1##R = 0.0f, t1##R = 0.5f; bool s1##R = false; \
    float m2##R = 0.0f, t2##R = 0.5f; bool s2##R = false; \
    float m3##R = 0.0f, t3##R = 0.5f; bool s3##R = false; \
    float c3f##R = 0.0f;
    ROWS(DECL_STATE)
#undef DECL_STATE

#define DECL_PTR(R) const float* xr##R = input + (size_t)n##R * T_STEPS;
    ROWS(DECL_PTR)
#undef DECL_PTR
    const float* cerow = ce + (size_t)lane * T_STEPS;    // ce is [H][T]

#define DECL_X(R) float x##R##_cur = xr##R[0];
    ROWS(DECL_X)
#undef DECL_X
    float co_cur = cerow[0];

#pragma unroll 1
    for (int t = 0; t < T_STEPS; ++t) {
        const int tn = (t < T_STEPS - 1) ? (t + 1) : (T_STEPS - 1);
#define LOAD_XN(R) const float x##R##_nxt = xr##R[tn];
        ROWS(LOAD_XN)
#undef LOAD_XN
        const float co_nxt = cerow[tn];
        const float co = co_cur;

        // ================= layer 1 =================
#define L1(R) { THUP(t1##R, m1##R) \
    const float h_ = (x##R##_cur * w1) + bb1; MEMUP(m1##R, s1##R, h_) }
        ROWS(L1)
#undef L1
#define CMP1(R) const bool p1##R = m1##R > t1##R; s1##R = p1##R;
        ROWS(CMP1)
#undef CMP1
        {
            f32x2 v0; v0.x = p1A ? 1.0f : 0.0f; v0.y = p1B ? 1.0f : 0.0f;
            f32x2 v1; v1.x = p1C ? 1.0f : 0.0f; v1.y = p1D ? 1.0f : 0.0f;
            f32x2 v2; v2.x = p1E ? 1.0f : 0.0f; v2.y = p1F ? 1.0f : 0.0f;
            f32x2 v3; v3.x = p1G ? 1.0f : 0.0f; v3.y = p1H ? 1.0f : 0.0f;
            sAB[lane] = v0; sCD[lane] = v1; sEF[lane] = v2; sGH[lane] = v3;
        }

        // ================= layer 2 =================
#define TH2(R) THUP(t2##R, m2##R)
        ROWS(TH2)
#undef TH2
        {
            f32x2 aAB; aAB.x = 0.0f; aAB.y = 0.0f;
            f32x2 aCD; aCD.x = 0.0f; aCD.y = 0.0f;
            f32x2 aEF; aEF.x = 0.0f; aEF.y = 0.0f;
            f32x2 aGH; aGH.x = 0.0f; aGH.y = 0.0f;
#pragma unroll
            for (int g = 0; g < 32; ++g) {
                const f32x4 qab = *reinterpret_cast<const f32x4*>(&sAB[2 * g]); // uniform b128
                const f32x4 qcd = *reinterpret_cast<const f32x4*>(&sCD[2 * g]);
                const f32x4 qef = *reinterpret_cast<const f32x4*>(&sEF[2 * g]);
                const f32x4 qgh = *reinterpret_cast<const f32x4*>(&sGH[2 * g]);
                PK_LO(aAB, __builtin_shufflevector(qab, qab, 0, 1), wp2[g]);
                PK_LO(aCD, __builtin_shufflevector(qcd, qcd, 0, 1), wp2[g]);
                PK_LO(aEF, __builtin_shufflevector(qef, qef, 0, 1), wp2[g]);
                PK_LO(aGH, __builtin_shufflevector(qgh, qgh, 0, 1), wp2[g]);
                PK_HI(aAB, __builtin_shufflevector(qab, qab, 2, 3), wp2[g]);
                PK_HI(aCD, __builtin_shufflevector(qcd, qcd, 2, 3), wp2[g]);
                PK_HI(aEF, __builtin_shufflevector(qef, qef, 2, 3), wp2[g]);
                PK_HI(aGH, __builtin_shufflevector(qgh, qgh, 2, 3), wp2[g]);
            }
            const float hA = aAB.x + bb2; MEMUP(m2A, s2A, hA)
            const float hB = aAB.y + bb2; MEMUP(m2B, s2B, hB)
            const float hC = aCD.x + bb2; MEMUP(m2C, s2C, hC)
            const float hD = aCD.y + bb2; MEMUP(m2D, s2D, hD)
            const float hE = aEF.x + bb2; MEMUP(m2E, s2E, hE)
            const float hF = aEF.y + bb2; MEMUP(m2F, s2F, hF)
            const float hG = aGH.x + bb2; MEMUP(m2G, s2G, hG)
            const float hH = aGH.y + bb2; MEMUP(m2H, s2H, hH)
        }
#define CMP2(R) const bool p2##R = m2##R > t2##R; s2##R = p2##R;
        ROWS(CMP2)
#undef CMP2
        {
            f32x2 v0; v0.x = p2A ? 1.0f : 0.0f; v0.y = p2B ? 1.0f : 0.0f;
            f32x2 v1; v1.x = p2C ? 1.0f : 0.0f; v1.y = p2D ? 1.0f : 0.0f;
            f32x2 v2; v2.x = p2E ? 1.0f : 0.0f; v2.y = p2F ? 1.0f : 0.0f;
            f32x2 v3; v3.x = p2G ? 1.0f : 0.0f; v3.y = p2H ? 1.0f : 0.0f;
            sAB[lane] = v0; sCD[lane] = v1; sEF[lane] = v2; sGH[lane] = v3;
        }

        // ================= layer 3 =================
#define TH3(R) THUP(t3##R, m3##R)
        ROWS(TH3)
#undef TH3
        {
            f32x2 aAB; aAB.x = 0.0f; aAB.y = 0.0f;
            f32x2 aCD; aCD.x = 0.0f; aCD.y = 0.0f;
            f32x2 aEF; aEF.x = 0.0f; aEF.y = 0.0f;
            f32x2 aGH; aGH.x = 0.0f; aGH.y = 0.0f;
#pragma unroll
            for (int g = 0; g < 32; ++g) {
                const f32x4 qab = *reinterpret_cast<const f32x4*>(&sAB[2 * g]);
                const f32x4 qcd = *reinterpret_cast<const f32x4*>(&sCD[2 * g]);
                const f32x4 qef = *reinterpret_cast<const f32x4*>(&sEF[2 * g]);
                const f32x4 qgh = *reinterpret_cast<const f32x4*>(&sGH[2 * g]);
                PK_LO(aAB, __builtin_shufflevector(qab, qab, 0, 1), wp3[g]);
                PK_LO(aCD, __builtin_shufflevector(qcd, qcd, 0, 1), wp3[g]);
                PK_LO(aEF, __builtin_shufflevector(qef, qef, 0, 1), wp3[g]);
                PK_LO(aGH, __builtin_shufflevector(qgh, qgh, 0, 1), wp3[g]);
                PK_HI(aAB, __builtin_shufflevector(qab, qab, 2, 3), wp3[g]);
                PK_HI(aCD, __builtin_shufflevector(qcd, qcd, 2, 3), wp3[g]);
                PK_HI(aEF, __builtin_shufflevector(qef, qef, 2, 3), wp3[g]);
                PK_HI(aGH, __builtin_shufflevector(qgh, qgh, 2, 3), wp3[g]);
            }
            const float hA = aAB.x + bb3; MEMUP(m3A, s3A, hA)
            const float hB = aAB.y + bb3; MEMUP(m3B, s3B, hB)
            const float hC = aCD.x + bb3; MEMUP(m3C, s3C, hC)
            const float hD = aCD.y + bb3; MEMUP(m3D, s3D, hD)
            const float hE = aEF.x + bb3; MEMUP(m3E, s3E, hE)
            const float hF = aEF.y + bb3; MEMUP(m3F, s3F, hF)
            const float hG = aGH.x + bb3; MEMUP(m3G, s3G, hG)
            const float hH = aGH.y + bb3; MEMUP(m3H, s3H, hH)
        }
#define CMP3(R) const bool p3##R = m3##R > t3##R; s3##R = p3##R; \
        c3f##R += p3##R ? 1.0f : 0.0f;
        ROWS(CMP3)
#undef CMP3

#define ROT_X(R) x##R##_cur = x##R##_nxt;
        ROWS(ROT_X)
#undef ROT_X
        co_cur = co_nxt;
    }

    // ---- epilogue: out[n][o] = (sum_t s3) @ Wo.T / T + bo ----
#define DECL_RES(R) const double cc##R = (double)c3f##R; double rr##R = 0.0;
    ROWS(DECL_RES)
#undef DECL_RES
#pragma unroll
    for (int o = 0; o < NOUT; ++o) {
        const double wo = (double)Wo[o * NH + lane];
#define MUL_V(R) double v##R = cc##R * wo;
        ROWS(MUL_V)
#undef MUL_V
#pragma unroll
        for (int off = 32; off; off >>= 1) {
#define RED_V(R) v##R += __shfl_xor(v##R, off, 64);
            ROWS(RED_V)
#undef RED_V
        }
        if (lane == o) {
#define SET_R(R) rr##R = v##R;
            ROWS(SET_R)
#undef SET_R
        }
    }
    if (lane < NOUT) {
        const double bod = (double)bo[lane];
        out[(size_t)nA * NOUT + lane] = (float)(rrA / (double)T_STEPS + bod);
        if (n0 + 1 < N) out[(size_t)nB * NOUT + lane] = (float)(rrB / (double)T_STEPS + bod);
        if (n0 + 2 < N) out[(size_t)nC * NOUT + lane] = (float)(rrC / (double)T_STEPS + bod);
        if (n0 + 3 < N) out[(size_t)nD * NOUT + lane] = (float)(rrD / (double)T_STEPS + bod);
        if (n0 + 4 < N) out[(size_t)nE * NOUT + lane] = (float)(rrE / (double)T_STEPS + bod);
        if (n0 + 5 < N) out[(size_t)nF * NOUT + lane] = (float)(rrF / (double)T_STEPS + bod);
        if (n0 + 6 < N) out[(size_t)nG * NOUT + lane] = (float)(rrG / (double)T_STEPS + bod);
        if (n0 + 7 < N) out[(size_t)nH * NOUT + lane] = (float)(rrH / (double)T_STEPS + bod);
    }
}

extern "C" void kernel_launch(void* const* d_in, const int* in_sizes, int n_in,
                              void* d_out, int out_size, void* d_ws, size_t ws_size,
                              hipStream_t stream) {
    const float* input = (const float*)d_in[0];
    const float* W1 = (const float*)d_in[1];
    const float* b1 = (const float*)d_in[2];
    const float* W2 = (const float*)d_in[3];
    const float* b2 = (const float*)d_in[4];
    const float* W3 = (const float*)d_in[5];
    const float* b3 = (const float*)d_in[6];
    const float* Wo = (const float*)d_in[7];
    const float* bo = (const float*)d_in[8];
    const float* ce = (const float*)d_in[9];
    float* out = (float*)d_out;

    const int N = in_sizes[0] / T_STEPS;

    hipLaunchKernelGGL(tesnn_main_kernel,
                       dim3((N + 7) / 8), dim3(64), 0, stream,
                       input, W1, b1, W2, b2, W3, b3, Wo, bo, ce, out, N);
}

// Round 19
// 4628.123 us; speedup vs baseline: 1.1317x; 1.1317x over previous
//
#include <hip/hip_runtime.h>
#include <stdint.h>

#pragma clang fp contract(off)

#define T_STEPS 784
#define NH 64
#define NOUT 10

// v_fma_mix_f32: D.f32 = fma(cvt_f32(S0.f16_half), S1.f32, S2.f32).
// f16 0.0/1.0 convert EXACTLY; then one IEEE-rn f32 fma -> per-row ascending-k
// single-accumulator chain is bit-identical to the __fmaf_rn chain.
// Syntax + numerics VERIFIED on hardware in round 11 (absmax 0.0009765625).
#define MIX_LO(acc, s, w) \
    asm("v_fma_mix_f32 %0, %1, %2, %0 op_sel:[0,0,0] op_sel_hi:[1,0,0]" \
        : "+v"(acc) : "v"(s), "v"(w))
#define MIX_HI(acc, s, w) \
    asm("v_fma_mix_f32 %0, %1, %2, %0 op_sel:[1,0,0] op_sel_hi:[1,0,0]" \
        : "+v"(acc) : "v"(s), "v"(w))

// th = (th + mem*co) - ((th-0.5)*0.02), each op rounded, old mem  (r3-verified)
#define THUP(tt, mm) { const float p_ = (mm) * co; const float q_ = (tt) + p_; \
    const float r_ = (tt) - 0.5f; const float rs_ = r_ * 0.02f; (tt) = q_ - rs_; }
// mem = (spike ? 0 : mem*0.5) + h   (r3-verified)
#define MEMUP(mm, ss, hh) { const float md_ = (mm) * 0.5f; \
    const float keep_ = (ss) ? 0.0f : md_; (mm) = keep_ + (hh); }

#define H16_ONE_LO 0x00003C00u
#define H16_ONE_HI 0x3C000000u

// TWO rows per wave; lane = neuron j. Spikes packed f16 {a|b} = ONE u32 per
// neuron -> one uniform-address b128 read covers FOUR neurons: 16 DS reads
// per layer (4x fewer than the f32 4-row scheme per row). DS was the measured
// wall (~0.19 inst/cyc/CU across r6-r17); v_fma_mix consumes the f16 halves
// directly so the VALU cost stays ~1 fma-class inst per row-k.

__global__ __attribute__((amdgpu_flat_work_group_size(64, 64)))
void tesnn_main_kernel(
    const float* __restrict__ input,
    const float* __restrict__ W1, const float* __restrict__ b1,
    const float* __restrict__ W2, const float* __restrict__ b2,
    const float* __restrict__ W3, const float* __restrict__ b3,
    const float* __restrict__ Wo, const float* __restrict__ bo,
    const float* __restrict__ ce,
    float* __restrict__ out, int N)
{
    __shared__ alignas(16) uint32_t sS[NH];   // spikes f16 {a,b}; reused L1->L2->L3

    const int lane = threadIdx.x;
    const int n0 = blockIdx.x * 2;
    if (n0 >= N) return;
    const int na = n0;
    const int nb = (n0 + 1 < N) ? n0 + 1 : N - 1;

    // ---- per-lane weights (lane = neuron j); scalar f32 (mix src1) ----
    const float w1 = W1[lane];
    const float bb1 = b1[lane];
    const float bb2 = b2[lane];
    const float bb3 = b3[lane];

    float w2r[NH], w3r[NH];
#pragma unroll
    for (int q = 0; q < 16; ++q) {
        float4 a = ((const float4*)W2)[lane * 16 + q];
        w2r[4 * q + 0] = a.x; w2r[4 * q + 1] = a.y;
        w2r[4 * q + 2] = a.z; w2r[4 * q + 3] = a.w;
        float4 b = ((const float4*)W3)[lane * 16 + q];
        w3r[4 * q + 0] = b.x; w3r[4 * q + 1] = b.y;
        w3r[4 * q + 2] = b.z; w3r[4 * q + 3] = b.w;
    }

    // ---- state (rows a, b) ----
    float m1a = 0.0f, t1a = 0.5f; bool s1a = false;
    float m1b = 0.0f, t1b = 0.5f; bool s1b = false;
    float m2a = 0.0f, t2a = 0.5f; bool s2a = false;
    float m2b = 0.0f, t2b = 0.5f; bool s2b = false;
    float m3a = 0.0f, t3a = 0.5f; bool s3a = false;
    float m3b = 0.0f, t3b = 0.5f; bool s3b = false;
    float c3fa = 0.0f, c3fb = 0.0f;

    const float* xra = input + (size_t)na * T_STEPS;
    const float* xrb = input + (size_t)nb * T_STEPS;
    const float* cerow = ce + (size_t)lane * T_STEPS;    // ce is [H][T]

    float xa_cur = xra[0], xb_cur = xrb[0];
    float co_cur = cerow[0];

#pragma unroll 1
    for (int t = 0; t < T_STEPS; ++t) {
        const int tn = (t < T_STEPS - 1) ? (t + 1) : (T_STEPS - 1);
        const float xa_nxt = xra[tn];
        const float xb_nxt = xrb[tn];
        const float co_nxt = cerow[tn];

        const float xa = xa_cur, xb = xb_cur;
        const float co = co_cur;

        // ================= layer 1 =================
        THUP(t1a, m1a) THUP(t1b, m1b)
        {
            const float ha = (xa * w1) + bb1; MEMUP(m1a, s1a, ha)
            const float hb = (xb * w1) + bb1; MEMUP(m1b, s1b, hb)
        }
        const bool p1a = m1a > t1a; s1a = p1a;
        const bool p1b = m1b > t1b; s1b = p1b;
        sS[lane] = (p1a ? H16_ONE_LO : 0u) | (p1b ? H16_ONE_HI : 0u);  // ds_write_b32

        // ================= layer 2 =================
        THUP(t2a, m2a) THUP(t2b, m2b)
        {
            float accA = 0.0f, accB = 0.0f;
            const uint4* s4 = reinterpret_cast<const uint4*>(sS);
#pragma unroll
            for (int g = 0; g < 16; ++g) {
                const uint4 q = s4[g];            // neurons 4g..4g+3, uniform b128
                MIX_LO(accA, q.x, w2r[4 * g + 0]);
                MIX_HI(accB, q.x, w2r[4 * g + 0]);
                MIX_LO(accA, q.y, w2r[4 * g + 1]);
                MIX_HI(accB, q.y, w2r[4 * g + 1]);
                MIX_LO(accA, q.z, w2r[4 * g + 2]);
                MIX_HI(accB, q.z, w2r[4 * g + 2]);
                MIX_LO(accA, q.w, w2r[4 * g + 3]);
                MIX_HI(accB, q.w, w2r[4 * g + 3]);
            }
            const float h2a = accA + bb2; MEMUP(m2a, s2a, h2a)
            const float h2b = accB + bb2; MEMUP(m2b, s2b, h2b)
        }
        const bool p2a = m2a > t2a; s2a = p2a;
        const bool p2b = m2b > t2b; s2b = p2b;
        sS[lane] = (p2a ? H16_ONE_LO : 0u) | (p2b ? H16_ONE_HI : 0u);  // overwrite after reads

        // ================= layer 3 =================
        THUP(t3a, m3a) THUP(t3b, m3b)
        {
            float accA = 0.0f, accB = 0.0f;
            const uint4* s4 = reinterpret_cast<const uint4*>(sS);
#pragma unroll
            for (int g = 0; g < 16; ++g) {
                const uint4 q = s4[g];
                MIX_LO(accA, q.x, w3r[4 * g + 0]);
                MIX_HI(accB, q.x, w3r[4 * g + 0]);
                MIX_LO(accA, q.y, w3r[4 * g + 1]);
                MIX_HI(accB, q.y, w3r[4 * g + 1]);
                MIX_LO(accA, q.z, w3r[4 * g + 2]);
                MIX_HI(accB, q.z, w3r[4 * g + 2]);
                MIX_LO(accA, q.w, w3r[4 * g + 3]);
                MIX_HI(accB, q.w, w3r[4 * g + 3]);
            }
            const float h3a = accA + bb3; MEMUP(m3a, s3a, h3a)
            const float h3b = accB + bb3; MEMUP(m3b, s3b, h3b)
        }
        const bool p3a = m3a > t3a; s3a = p3a;
        const bool p3b = m3b > t3b; s3b = p3b;
        c3fa += p3a ? 1.0f : 0.0f;
        c3fb += p3b ? 1.0f : 0.0f;

        xa_cur = xa_nxt; xb_cur = xb_nxt;
        co_cur = co_nxt;
    }

    // ---- epilogue: out[n][o] = (sum_t s3) @ Wo.T / T + bo ----
    const double cA = (double)c3fa, cB = (double)c3fb;
    double rA = 0.0, rB = 0.0;
#pragma unroll
    for (int o = 0; o < NOUT; ++o) {
        const double wo = (double)Wo[o * NH + lane];
        double vA = cA * wo, vB = cB * wo;
#pragma unroll
        for (int off = 32; off; off >>= 1) {
            vA += __shfl_xor(vA, off, 64);
            vB += __shfl_xor(vB, off, 64);
        }
        if (lane == o) { rA = vA; rB = vB; }
    }
    if (lane < NOUT) {
        const double bod = (double)bo[lane];
        out[(size_t)na * NOUT + lane] = (float)(rA / (double)T_STEPS + bod);
        if (n0 + 1 < N)
            out[(size_t)nb * NOUT + lane] = (float)(rB / (double)T_STEPS + bod);
    }
}

extern "C" void kernel_launch(void* const* d_in, const int* in_sizes, int n_in,
                              void* d_out, int out_size, void* d_ws, size_t ws_size,
                              hipStream_t stream) {
    const float* input = (const float*)d_in[0];
    const float* W1 = (const float*)d_in[1];
    const float* b1 = (const float*)d_in[2];
    const float* W2 = (const float*)d_in[3];
    const float* b2 = (const float*)d_in[4];
    const float* W3 = (const float*)d_in[5];
    const float* b3 = (const float*)d_in[6];
    const float* Wo = (const float*)d_in[7];
    const float* bo = (const float*)d_in[8];
    const float* ce = (const float*)d_in[9];
    float* out = (float*)d_out;

    const int N = in_sizes[0] / T_STEPS;

    hipLaunchKernelGGL(tesnn_main_kernel,
                       dim3((N + 1) / 2), dim3(64), 0, stream,
                       input, W1, b1, W2, b2, W3, b3, Wo, bo, ce, out, N);
}